// Round 1
// baseline (112.204 us; speedup 1.0000x reference)
//
#include <hip/hip_runtime.h>
#include <hip/hip_bf16.h>

using bf16 = __hip_bfloat16;
typedef short short8 __attribute__((ext_vector_type(8)));
typedef float floatx4 __attribute__((ext_vector_type(4)));

#define NROWS 8192
#define DIM 512

#define AS1(p) ((const __attribute__((address_space(1))) void*)(p))
#define AS3(p) ((__attribute__((address_space(3))) void*)(p))

// ---------------------------------------------------------------------------
// Kernel 1: per-row L2 normalize (fp32 -> bf16), per-row diag dot, zero rowsum
// ---------------------------------------------------------------------------
__global__ __launch_bounds__(256) void prep_kernel(
    const float* __restrict__ v, const float* __restrict__ u,
    bf16* __restrict__ vn, bf16* __restrict__ un,
    float* __restrict__ diag, float* __restrict__ rowsum)
{
    const int row = blockIdx.x;
    const int t = threadIdx.x;
    const float2 a = reinterpret_cast<const float2*>(v + (size_t)row * DIM)[t];
    const float2 b = reinterpret_cast<const float2*>(u + (size_t)row * DIM)[t];
    float sv = a.x * a.x + a.y * a.y;
    float su = b.x * b.x + b.y * b.y;
    float sd = a.x * b.x + a.y * b.y;
#pragma unroll
    for (int m = 32; m; m >>= 1) {
        sv += __shfl_xor(sv, m);
        su += __shfl_xor(su, m);
        sd += __shfl_xor(sd, m);
    }
    __shared__ float red[3][4];
    const int wave = t >> 6;
    if ((t & 63) == 0) { red[0][wave] = sv; red[1][wave] = su; red[2][wave] = sd; }
    __syncthreads();
    sv = red[0][0] + red[0][1] + red[0][2] + red[0][3];
    su = red[1][0] + red[1][1] + red[1][2] + red[1][3];
    sd = red[2][0] + red[2][1] + red[2][2] + red[2][3];
    const float rv = 1.0f / fmaxf(sqrtf(sv), 1e-8f);
    const float ru = 1.0f / fmaxf(sqrtf(su), 1e-8f);
    __hip_bfloat162 ov, ou;
    ov.x = __float2bfloat16(a.x * rv); ov.y = __float2bfloat16(a.y * rv);
    ou.x = __float2bfloat16(b.x * ru); ou.y = __float2bfloat16(b.y * ru);
    reinterpret_cast<__hip_bfloat162*>(vn + (size_t)row * DIM)[t] = ov;
    reinterpret_cast<__hip_bfloat162*>(un + (size_t)row * DIM)[t] = ou;
    if (t == 0) {
        diag[row] = sd * rv * ru;
        rowsum[row] = 0.0f;
    }
}

// ---------------------------------------------------------------------------
// Kernel 2: sim = vn . un^T tile GEMM (128x128, BK=32, 4 waves), fused
// exp(sim/T) row-sum epilogue with one atomicAdd per row per block.
// ---------------------------------------------------------------------------
__global__ __launch_bounds__(256, 2) void simsum_kernel(
    const bf16* __restrict__ A, const bf16* __restrict__ Bm,
    float* __restrict__ rowsum)
{
    __shared__ bf16 lA[128 * 32];   // [row][k] row-major, 8 KB
    __shared__ bf16 lB[128 * 32];
    const int t = threadIdx.x;
    const int wave = t >> 6, lane = t & 63;
    const int brow = blockIdx.x, bcol = blockIdx.y;
    const int wr = wave >> 1, wc = wave & 1;   // 2x2 waves, 64x64 each

    floatx4 acc[4][4];
#pragma unroll
    for (int m = 0; m < 4; ++m)
#pragma unroll
        for (int n = 0; n < 4; ++n)
            acc[m][n] = (floatx4){0.f, 0.f, 0.f, 0.f};

    // staging: thread t loads 16B (8 bf16) of row t/4, chunk t%4
    const int lrow = t >> 2;
    const int lcol = (t & 3) * 8;
    const bf16* gA = A + (size_t)(brow * 128 + lrow) * DIM + lcol;
    const bf16* gB = Bm + (size_t)(bcol * 128 + lrow) * DIM + lcol;
    bf16* lAw = lA + wave * 512;   // wave-uniform LDS base (bytes = wave*1024)
    bf16* lBw = lB + wave * 512;

    const int arow = wr * 64 + (lane & 15);
    const int brw  = wc * 64 + (lane & 15);
    const int koff = (lane >> 4) * 8;

    for (int k = 0; k < 16; ++k) {
        const bf16* ga = gA + k * 32;
        const bf16* gb = gB + k * 32;
        __builtin_amdgcn_global_load_lds(AS1(ga),            AS3(lAw),        16, 0, 0);
        __builtin_amdgcn_global_load_lds(AS1(ga + 64 * DIM), AS3(lAw + 2048), 16, 0, 0);
        __builtin_amdgcn_global_load_lds(AS1(gb),            AS3(lBw),        16, 0, 0);
        __builtin_amdgcn_global_load_lds(AS1(gb + 64 * DIM), AS3(lBw + 2048), 16, 0, 0);
        __syncthreads();   // compiler drains vmcnt before barrier

        short8 af[4], bfr[4];
#pragma unroll
        for (int m = 0; m < 4; ++m)
            af[m] = *reinterpret_cast<const short8*>(&lA[(arow + m * 16) * 32 + koff]);
#pragma unroll
        for (int n = 0; n < 4; ++n)
            bfr[n] = *reinterpret_cast<const short8*>(&lB[(brw + n * 16) * 32 + koff]);
#pragma unroll
        for (int m = 0; m < 4; ++m)
#pragma unroll
            for (int n = 0; n < 4; ++n)
                acc[m][n] = __builtin_amdgcn_mfma_f32_16x16x32_bf16(
                    af[m], bfr[n], acc[m][n], 0, 0, 0);
        __syncthreads();   // all reads done before next stage overwrites
    }

    // epilogue: rowsum += sum over this block's 128 cols of exp(sim * 2)
    // C/D layout: col = lane&15, row = (lane>>4)*4 + reg  [m89/m91 verified]
#pragma unroll
    for (int m = 0; m < 4; ++m) {
#pragma unroll
        for (int r = 0; r < 4; ++r) {
            float s = 0.f;
#pragma unroll
            for (int n = 0; n < 4; ++n)
                s += expf(acc[m][n][r] * 2.0f);
            // reduce across the 16 lanes holding cols 0..15 of the same rows
            s += __shfl_xor(s, 1);
            s += __shfl_xor(s, 2);
            s += __shfl_xor(s, 4);
            s += __shfl_xor(s, 8);
            if ((lane & 15) == 0) {
                const int grow = brow * 128 + wr * 64 + m * 16 + (lane >> 4) * 4 + r;
                atomicAdd(&rowsum[grow], s);
            }
        }
    }
}

// ---------------------------------------------------------------------------
// Kernel 3: loss_i = log(exp(2*diag_i) + rowsum_i) - 2*diag_i
// ---------------------------------------------------------------------------
__global__ __launch_bounds__(256) void loss_kernel(
    const float* __restrict__ diag, const float* __restrict__ rowsum,
    float* __restrict__ out)
{
    const int i = blockIdx.x * 256 + threadIdx.x;
    const float d2 = diag[i] * 2.0f;
    out[i] = logf(expf(d2) + rowsum[i]) - d2;
}

extern "C" void kernel_launch(void* const* d_in, const int* in_sizes, int n_in,
                              void* d_out, int out_size, void* d_ws, size_t ws_size,
                              hipStream_t stream) {
    const float* v = (const float*)d_in[0];
    const float* u = (const float*)d_in[1];
    float* out = (float*)d_out;
    char* ws = (char*)d_ws;
    bf16* vn     = (bf16*)ws;                               // 8 MiB
    bf16* un     = (bf16*)(ws + (size_t)8388608);           // 8 MiB
    float* diag  = (float*)(ws + (size_t)2 * 8388608);      // 32 KiB
    float* rowsum= (float*)(ws + (size_t)2 * 8388608 + 32768); // 32 KiB

    prep_kernel<<<NROWS, 256, 0, stream>>>(v, u, vn, un, diag, rowsum);
    dim3 grid(64, 64);
    simsum_kernel<<<grid, 256, 0, stream>>>(vn, un, rowsum);
    loss_kernel<<<NROWS / 256, 256, 0, stream>>>(diag, rowsum, out);
}